// Round 6
// baseline (10869.320 us; speedup 1.0000x reference)
//
#include <hip/hip_runtime.h>
#include <math.h>

// Problem constants (from reference)
#define B_ 32
#define N_ 16384
#define K_ 21
#define C_ 64
#define M_ (N_ - K_ + 1)   // 16364
#define T_ 30
// L = 10.0, LAM = 0.1  ->  1/L = 0.1, LAM/L = 0.01

#define TILE 236   // x outputs per block; res width = 256
#define XF4  69    // float4 per staged row (276 floats = TILE+40)
#define XP4  72    // padded row (multiple of 8 -> XOR swizzle stays in-row)
#define NSTG 3     // ceil(8*XF4 / 256) register-staging slots
#define NT   256   // 4 waves

// One block: batch b, x tile [m0, m0+TILE), 64 channels in 8 chunks of 8.
// Double-buffered LDS staging with async split: issue chunk k+1 global
// loads -> compute chunk k (latency hides under FMA) -> blend + ds_write
// -> barrier. Rows XOR-swizzled (i4 ^ (row&7)) to decorrelate the bank
// phase of the 4 rows concurrently read by the 4 waves.
// Wave wv computes convT partials for local rows {2wv, 2wv+1} per chunk;
// phase 3 re-reads x_tmp own-positions from global (L2-hot).
__global__ __launch_bounds__(NT, 6) void fused_step_kernel(
    const float* __restrict__ Xc, const float* __restrict__ Xo,
    float* __restrict__ Xw, const float* __restrict__ y,
    const float* __restrict__ Hg, const float bp, const float bm,
    const int first)
{
  __shared__ float4 xs4[2][8][XP4];   // 18432 B  double-buffered x_tmp chunk
  __shared__ float  rp[4][256];       //  4096 B  per-wave convT partials
  __shared__ float  rs[256];          //  1024 B  final residual row

  const int tid = threadIdx.x;
  const int wv  = tid >> 6;
  const int l   = tid & 63;
  const int b   = blockIdx.y;
  const int m0  = blockIdx.x * TILE;
  const int g0  = m0 - 20;
  const bool has_o = (bm != 0.f);

  if (!first) {
    float p0 = 0.f, p1 = 0.f, p2 = 0.f, p3 = 0.f;

    // ---- prologue: stage chunk 0 (channels 0..7) into buf 0 ----
    #pragma unroll
    for (int s = 0; s < NSTG; ++s) {
      const int f = tid + (s << 8);
      if (f < 8 * XF4) {
        const int r  = f / XF4;
        const int i4 = f - r * XF4;
        const int g  = g0 + (i4 << 2);
        const float* pa = Xc + ((size_t)b * C_ + r) * M_ + g;
        const float* po = Xo + ((size_t)b * C_ + r) * M_ + g;
        float4 a = make_float4(0.f,0.f,0.f,0.f);
        float4 o = make_float4(0.f,0.f,0.f,0.f);
        if (g >= 0 && g + 3 < M_) {
          a = *(const float4*)pa;
          if (has_o) o = *(const float4*)po;
        } else {
          if ((unsigned)(g+0) < (unsigned)M_) { a.x = pa[0]; if (has_o) o.x = po[0]; }
          if ((unsigned)(g+1) < (unsigned)M_) { a.y = pa[1]; if (has_o) o.y = po[1]; }
          if ((unsigned)(g+2) < (unsigned)M_) { a.z = pa[2]; if (has_o) o.z = po[2]; }
          if ((unsigned)(g+3) < (unsigned)M_) { a.w = pa[3]; if (has_o) o.w = po[3]; }
        }
        float4 w4;
        w4.x = fmaf(bm, o.x, bp * a.x);
        w4.y = fmaf(bm, o.y, bp * a.y);
        w4.z = fmaf(bm, o.z, bp * a.z);
        w4.w = fmaf(bm, o.w, bp * a.w);
        xs4[0][r][i4 ^ (r & 7)] = w4;
      }
    }
    __syncthreads();

    // ---- main chunk loop: issue loads k+1 | compute k | write k+1 ----
    for (int k = 0; k < 8; ++k) {
      const int bf = k & 1;
      const int kn = k + 1;

      float4 va[NSTG], vo[NSTG];
      int    fr[NSTG], fi[NSTG];
      bool   fok[NSTG];
      if (kn < 8) {
        const int ch0 = kn << 3;
        #pragma unroll
        for (int s = 0; s < NSTG; ++s) {
          const int f = tid + (s << 8);
          fok[s] = (f < 8 * XF4);
          float4 a = make_float4(0.f,0.f,0.f,0.f);
          float4 o = make_float4(0.f,0.f,0.f,0.f);
          int r = 0, i4 = 0;
          if (fok[s]) {
            r  = f / XF4;
            i4 = f - r * XF4;
            const int g = g0 + (i4 << 2);
            const float* pa = Xc + ((size_t)b * C_ + ch0 + r) * M_ + g;
            const float* po = Xo + ((size_t)b * C_ + ch0 + r) * M_ + g;
            if (g >= 0 && g + 3 < M_) {
              a = *(const float4*)pa;
              if (has_o) o = *(const float4*)po;
            } else {
              if ((unsigned)(g+0) < (unsigned)M_) { a.x = pa[0]; if (has_o) o.x = po[0]; }
              if ((unsigned)(g+1) < (unsigned)M_) { a.y = pa[1]; if (has_o) o.y = po[1]; }
              if ((unsigned)(g+2) < (unsigned)M_) { a.z = pa[2]; if (has_o) o.z = po[2]; }
              if ((unsigned)(g+3) < (unsigned)M_) { a.w = pa[3]; if (has_o) o.w = po[3]; }
            }
          }
          va[s] = a; vo[s] = o; fr[s] = r; fi[s] = i4 ^ (r & 7);
        }
      }

      // compute chunk k: wave wv handles local rows 2wv, 2wv+1
      #pragma unroll
      for (int j = 0; j < 2; ++j) {
        const int r  = (wv << 1) + j;
        const int cg = __builtin_amdgcn_readfirstlane((k << 3) + r);
        const float* hc = Hg + cg * K_;   // uniform -> s_loads
        float w[24];
        #pragma unroll
        for (int kk = 0; kk < 6; ++kk) {
          const float4 v = xs4[bf][r][(l + kk) ^ (r & 7)];
          w[4*kk+0] = v.x; w[4*kk+1] = v.y;
          w[4*kk+2] = v.z; w[4*kk+3] = v.w;
        }
        #pragma unroll
        for (int u = 0; u < 21; ++u) {
          const float hv = hc[20 - u];
          p0 = fmaf(w[u],     hv, p0);
          p1 = fmaf(w[u + 1], hv, p1);
          p2 = fmaf(w[u + 2], hv, p2);
          p3 = fmaf(w[u + 3], hv, p3);
        }
      }

      // blend + write staged chunk k+1 into the other buffer
      if (kn < 8) {
        const int bn = kn & 1;
        #pragma unroll
        for (int s = 0; s < NSTG; ++s) {
          if (fok[s]) {
            float4 w4;
            w4.x = fmaf(bm, vo[s].x, bp * va[s].x);
            w4.y = fmaf(bm, vo[s].y, bp * va[s].y);
            w4.z = fmaf(bm, vo[s].z, bp * va[s].z);
            w4.w = fmaf(bm, vo[s].w, bp * va[s].w);
            xs4[bn][fr[s]][fi[s]] = w4;
          }
        }
      }
      __syncthreads();
    }

    rp[wv][(l<<2)+0] = p0; rp[wv][(l<<2)+1] = p1;
    rp[wv][(l<<2)+2] = p2; rp[wv][(l<<2)+3] = p3;
  }
  __syncthreads();

  // ---- finalize residual ----
  {
    const int n = m0 + tid;
    float r = 0.f;
    if (n < N_) {
      r = y[(size_t)b * N_ + n];
      if (!first) r -= rp[0][tid] + rp[1][tid] + rp[2][tid] + rp[3][tid];
    }
    rs[tid] = r;
  }
  __syncthreads();

  // ---- gradient step + shrink: wave wv writes channels [16wv,16wv+16) ----
  if (l < 59 && (l << 2) < M_ - m0) {
    float wr[24];
    #pragma unroll
    for (int kk = 0; kk < 6; ++kk) {
      const float4 v = *(const float4*)&rs[(l << 2) + (kk << 2)];
      wr[4*kk+0] = v.x; wr[4*kk+1] = v.y;
      wr[4*kk+2] = v.z; wr[4*kk+3] = v.w;
    }
    #pragma unroll 4
    for (int cl = 0; cl < 16; ++cl) {
      const int cg = __builtin_amdgcn_readfirstlane((wv << 4) + cl);
      const size_t row = ((size_t)b * C_ + cg) * M_ + m0 + (l << 2);
      float xt0, xt1, xt2, xt3;
      if (!first) {
        const float4 a = *(const float4*)(Xc + row);
        float ox = 0.f, oy = 0.f, oz = 0.f, ow = 0.f;
        if (has_o) {
          const float4 o = *(const float4*)(Xo + row);
          ox = o.x; oy = o.y; oz = o.z; ow = o.w;
        }
        xt0 = fmaf(bm, ox, bp * a.x);
        xt1 = fmaf(bm, oy, bp * a.y);
        xt2 = fmaf(bm, oz, bp * a.z);
        xt3 = fmaf(bm, ow, bp * a.w);
      } else { xt0 = xt1 = xt2 = xt3 = 0.f; }

      const float* hc = Hg + cg * K_;
      float a0 = 0.f, a1 = 0.f, a2 = 0.f, a3 = 0.f;
      #pragma unroll
      for (int u = 0; u < 21; ++u) {
        const float hv = hc[u];
        a0 = fmaf(wr[u],     hv, a0);
        a1 = fmaf(wr[u + 1], hv, a1);
        a2 = fmaf(wr[u + 2], hv, a2);
        a3 = fmaf(wr[u + 3], hv, a3);
      }
      const float o0 = fmaxf(fmaf(a0, 0.1f, xt0) - 0.01f, 0.f);
      const float o1 = fmaxf(fmaf(a1, 0.1f, xt1) - 0.01f, 0.f);
      const float o2 = fmaxf(fmaf(a2, 0.1f, xt2) - 0.01f, 0.f);
      const float o3 = fmaxf(fmaf(a3, 0.1f, xt3) - 0.01f, 0.f);
      *(float4*)(Xw + row) = make_float4(o0, o1, o2, o3);
    }
  }
}

// ---------------- convT kernel for final y_hat (round-1, proven) ----------
#define TA 1024
#define CC 16
#define NTHR 256

__global__ __launch_bounds__(NTHR) void convT_kernel(
    const float* __restrict__ X, const float* __restrict__ y,
    const float* __restrict__ Hg, float* __restrict__ out,
    const int use_y, const float sign)
{
  __shared__ float xs[CC][TA + 20];
  __shared__ float hs[C_][K_];
  const int tid = threadIdx.x;
  const int b = blockIdx.y;
  const int n0 = blockIdx.x * TA;

  for (int f = tid; f < C_ * K_; f += NTHR) hs[f / K_][f % K_] = sign * Hg[f];

  float acc[4];
  if (use_y) {
    const float4 v = *(const float4*)(y + (size_t)b * N_ + n0 + tid * 4);
    acc[0] = v.x; acc[1] = v.y; acc[2] = v.z; acc[3] = v.w;
  } else {
    acc[0] = acc[1] = acc[2] = acc[3] = 0.f;
  }

  const bool interior = (n0 >= 20) && (n0 + TA - 1 <= M_ - 1);
  const int QROW = (TA + 20) / 4;

  for (int cb = 0; cb < C_; cb += CC) {
    __syncthreads();
    for (int f = tid; f < CC * QROW; f += NTHR) {
      const int c = f / QROW;
      const int i = (f % QROW) * 4;
      const int gx = n0 - 20 + i;
      const float* src = X + ((size_t)(b * C_ + cb + c)) * M_ + gx;
      float4 v;
      if (interior) {
        v = *(const float4*)src;
      } else {
        v.x = (gx >= 0     && gx < M_)     ? src[0] : 0.f;
        v.y = (gx + 1 >= 0 && gx + 1 < M_) ? src[1] : 0.f;
        v.z = (gx + 2 >= 0 && gx + 2 < M_) ? src[2] : 0.f;
        v.w = (gx + 3 >= 0 && gx + 3 < M_) ? src[3] : 0.f;
      }
      *(float4*)&xs[c][i] = v;
    }
    __syncthreads();

    for (int c = 0; c < CC; ++c) {
      float w[24];
      #pragma unroll
      for (int k = 0; k < 6; ++k) {
        const float4 v = *(const float4*)&xs[c][tid * 4 + k * 4];
        w[k*4] = v.x; w[k*4+1] = v.y; w[k*4+2] = v.z; w[k*4+3] = v.w;
      }
      const float* hr = hs[cb + c];
      #pragma unroll
      for (int j = 0; j < K_; ++j) {
        const float h = hr[j];
        acc[0] = fmaf(h, w[20 - j], acc[0]);
        acc[1] = fmaf(h, w[21 - j], acc[1]);
        acc[2] = fmaf(h, w[22 - j], acc[2]);
        acc[3] = fmaf(h, w[23 - j], acc[3]);
      }
    }
  }

  *(float4*)(out + (size_t)b * N_ + n0 + tid * 4) =
      make_float4(acc[0], acc[1], acc[2], acc[3]);
}

extern "C" void kernel_launch(void* const* d_in, const int* in_sizes, int n_in,
                              void* d_out, int out_size, void* d_ws, size_t ws_size,
                              hipStream_t stream)
{
  const float* y = (const float*)d_in[0];   // [B,1,N] fp32
  const float* H = (const float*)d_in[1];   // [C,1,K] fp32
  float* out  = (float*)d_out;
  float* outy = out;                         // [B,N] y_hat region
  float* outx = out + (size_t)B_ * N_;       // [B,C,M] x region

  const size_t SZ = (size_t)B_ * C_ * M_;    // floats per x buffer

  // FISTA momentum: betas[t] = (s_t - 1)/s_{t+1}, s_0 = 1 (betas[0] = 0)
  float betas[T_];
  double s = 1.0;
  for (int t = 0; t < T_; ++t) {
    const double sn = (1.0 + sqrt(1.0 + 4.0 * s * s)) * 0.5;
    betas[t] = (float)((s - 1.0) / sn);
    s = sn;
  }

  // 3 rotating x buffers; rotation lands x_30 in outx at t=29.
  float* P[3] = { (float*)d_ws, (float*)d_ws + SZ, outx };
  const dim3 blk(NT);
  const dim3 gF((M_ + TILE - 1) / TILE, B_);   // 70 x 32
  for (int t = 0; t < T_; ++t) {
    const float beta = (t >= 1) ? betas[t - 1] : 0.f;
    const float* Xc = P[(t + 2) % 3];          // x_t     (unused when t==0)
    const float* Xo = (beta != 0.f) ? P[(t + 1) % 3] : Xc;   // x_{t-1}
    float*       Xw = P[t % 3];                // x_{t+1}
    fused_step_kernel<<<gF, blk, 0, stream>>>(Xc, Xo, Xw, y, H,
                                              1.f + beta, -beta, t == 0);
  }
  const dim3 gA(N_ / TA, B_);
  convT_kernel<<<gA, dim3(NTHR), 0, stream>>>(outx, y, H, outy, 0, 1.f);
}

// Round 8
// 2994.975 us; speedup vs baseline: 3.6292x; 3.6292x over previous
//
#include <hip/hip_runtime.h>
#include <math.h>

// Problem constants (from reference)
#define B_ 32
#define N_ 16384
#define K_ 21
#define C_ 64
#define M_ (N_ - K_ + 1)   // 16364
#define T_ 30
// L = 10.0, LAM = 0.1  ->  1/L = 0.1, LAM/L = 0.01

#define TILE 236    // x outputs per block
#define NBLK 70     // blocks per batch in m  (70*236 >= M_)
#define UPW  256    // u-partial slots per block (res width)
#define XRW  280    // LDS x row width: 20 zero pad + 236 + 24 pad
#define NT   256    // 4 waves

// ---------------- round-8 fused step ----------------
// u_t = convT(x_t) kept as per-block partials up[B][NBLK][UPW] (<=2 blocks
// overlap per position -> exact deterministic sum at read time, no atomics).
// Per block (b, x): res tile from y/u (tiny, L2-hot); conv(res)+shrink from
// rs in LDS; x_{t+1} written to global AND to LDS rows; convT partials of
// the new tile accumulate this block's up_{t+1} slots. NO global halo
// staging anywhere. All cross-lane LDS reads are barrier-separated.
__global__ __launch_bounds__(NT) void fused_step2_kernel(
    const float* __restrict__ Xc, const float* __restrict__ Xo,
    float* __restrict__ Xw,
    const float* __restrict__ Ut, const float* __restrict__ Uo,
    float* __restrict__ Uw,
    const float* __restrict__ y, const float* __restrict__ Hg,
    const float bp, const float bm, const int first)
{
  __shared__ float rs[256];        // residual row
  __shared__ float xr[16][XRW];    // x_{t+1} chunk rows (17920 B)
  __shared__ float rp[4][256];     // per-wave convT partials

  const int tid = threadIdx.x;
  const int wv  = tid >> 6;
  const int l   = tid & 63;
  const int b   = blockIdx.y;
  const int x   = blockIdx.x;
  const int m0  = x * TILE;
  const bool has_o = (bm != 0.f);

  // ---- zero xr (pads + last-block tail stay zero forever) ----
  {
    float4* p = (float4*)&xr[0][0];
    #pragma unroll
    for (int s = 0; s < 5; ++s) {
      const int idx = tid + (s << 8);
      if (idx < 16 * XRW / 4) p[idx] = make_float4(0.f, 0.f, 0.f, 0.f);
    }
  }

  // ---- residual: res = y - bp*u_t - bm*u_{t-1} ----
  {
    const int n = m0 + tid;
    float r = 0.f;
    if (n < N_) {
      r = y[(size_t)b * N_ + n];
      if (!first) {
        const float* Ub = Ut + (size_t)b * NBLK * UPW;
        float ut;
        if (tid >= 236) {
          ut = Ub[(x + 1) * UPW + tid - 236] + Ub[x * UPW + tid];
        } else {
          ut = Ub[x * UPW + tid];
          if (tid < 20 && x > 0) ut += Ub[(x - 1) * UPW + 236 + tid];
        }
        r -= bp * ut;
        if (has_o) {
          const float* Vb = Uo + (size_t)b * NBLK * UPW;
          float uo;
          if (tid >= 236) {
            uo = Vb[(x + 1) * UPW + tid - 236] + Vb[x * UPW + tid];
          } else {
            uo = Vb[x * UPW + tid];
            if (tid < 20 && x > 0) uo += Vb[(x - 1) * UPW + 236 + tid];
          }
          r -= bm * uo;
        }
      }
    }
    rs[tid] = r;
  }
  __syncthreads();

  const int rem = M_ - m0;
  const bool act = (l < 59) && ((l << 2) < rem);
  float p0 = 0.f, p1 = 0.f, p2 = 0.f, p3 = 0.f;

  for (int k = 0; k < 4; ++k) {   // 4 chunks x 16 channels
    // ---- phase A: conv(res) + shrink; write x to global + LDS row ----
    if (act) {
      float wr[24];
      #pragma unroll
      for (int kk = 0; kk < 6; ++kk) {
        const float4 v = *(const float4*)&rs[(l << 2) + (kk << 2)];
        wr[4*kk+0] = v.x; wr[4*kk+1] = v.y;
        wr[4*kk+2] = v.z; wr[4*kk+3] = v.w;
      }
      #pragma unroll
      for (int j = 0; j < 4; ++j) {
        const int row = (wv << 2) + j;
        const int cg  = __builtin_amdgcn_readfirstlane((k << 4) + row);
        const size_t gro = ((size_t)b * C_ + cg) * M_ + m0 + (l << 2);
        float xt0 = 0.f, xt1 = 0.f, xt2 = 0.f, xt3 = 0.f;
        if (!first) {
          const float4 a = *(const float4*)(Xc + gro);
          float ox = 0.f, oy = 0.f, oz = 0.f, ow = 0.f;
          if (has_o) {
            const float4 o = *(const float4*)(Xo + gro);
            ox = o.x; oy = o.y; oz = o.z; ow = o.w;
          }
          xt0 = fmaf(bm, ox, bp * a.x);
          xt1 = fmaf(bm, oy, bp * a.y);
          xt2 = fmaf(bm, oz, bp * a.z);
          xt3 = fmaf(bm, ow, bp * a.w);
        }
        const float* hc = Hg + cg * K_;   // uniform -> s_loads
        float g0 = 0.f, g1 = 0.f, g2 = 0.f, g3 = 0.f;
        #pragma unroll
        for (int u = 0; u < 21; ++u) {
          const float hv = hc[u];
          g0 = fmaf(wr[u],     hv, g0);
          g1 = fmaf(wr[u + 1], hv, g1);
          g2 = fmaf(wr[u + 2], hv, g2);
          g3 = fmaf(wr[u + 3], hv, g3);
        }
        const float o0 = fmaxf(fmaf(g0, 0.1f, xt0) - 0.01f, 0.f);
        const float o1 = fmaxf(fmaf(g1, 0.1f, xt1) - 0.01f, 0.f);
        const float o2 = fmaxf(fmaf(g2, 0.1f, xt2) - 0.01f, 0.f);
        const float o3 = fmaxf(fmaf(g3, 0.1f, xt3) - 0.01f, 0.f);
        *(float4*)(Xw + gro) = make_float4(o0, o1, o2, o3);
        *(float4*)&xr[row][20 + (l << 2)] = make_float4(o0, o1, o2, o3);
      }
    }
    __syncthreads();

    // ---- phase B: convT partials of the new x tile (LDS windows) ----
    #pragma unroll
    for (int j = 0; j < 4; ++j) {
      const int row = (wv << 2) + j;
      const int cg  = __builtin_amdgcn_readfirstlane((k << 4) + row);
      const float* hc = Hg + cg * K_;
      float w[24];
      #pragma unroll
      for (int kk = 0; kk < 6; ++kk) {
        const float4 v = *(const float4*)&xr[row][(l << 2) + (kk << 2)];
        w[4*kk+0] = v.x; w[4*kk+1] = v.y;
        w[4*kk+2] = v.z; w[4*kk+3] = v.w;
      }
      #pragma unroll
      for (int u = 0; u < 21; ++u) {
        const float hv = hc[20 - u];
        p0 = fmaf(w[u],     hv, p0);
        p1 = fmaf(w[u + 1], hv, p1);
        p2 = fmaf(w[u + 2], hv, p2);
        p3 = fmaf(w[u + 3], hv, p3);
      }
    }
    __syncthreads();   // before next chunk's phase A overwrites rows
  }

  rp[wv][(l<<2)+0] = p0; rp[wv][(l<<2)+1] = p1;
  rp[wv][(l<<2)+2] = p2; rp[wv][(l<<2)+3] = p3;
  __syncthreads();

  // one deterministic write per slot
  Uw[((size_t)b * NBLK + x) * UPW + tid] =
      rp[0][tid] + rp[1][tid] + rp[2][tid] + rp[3][tid];
}

// y_hat[n] = u_30(n) from per-block partials (<=2 contributions)
__global__ __launch_bounds__(NT) void yhat_combine_kernel(
    const float* __restrict__ Uw, float* __restrict__ outy)
{
  const int tid = threadIdx.x;
  const int n = blockIdx.x * 256 + tid;
  const int b = blockIdx.y;
  const int x = n / 236;
  const int i = n - x * 236;
  const float* Ub = Uw + (size_t)b * NBLK * UPW;
  float v = Ub[x * UPW + i];
  if (i < 20 && x > 0) v += Ub[(x - 1) * UPW + 236 + i];
  outy[(size_t)b * N_ + n] = v;
}

// ================= round-5 proven fallback path =================
#define XWID 276
#define Q4PC 69
#define NQ4  (16 * Q4PC)

__global__ __launch_bounds__(NT, 4) void fused_step_r5_kernel(
    const float* __restrict__ Xc, const float* __restrict__ Xo,
    float* __restrict__ Xw, const float* __restrict__ y,
    const float* __restrict__ Hg, const float bp, const float bm,
    const int first)
{
  __shared__ float xs[16][XWID];
  __shared__ float rp[4][256];
  __shared__ float rs[256];

  const int tid = threadIdx.x;
  const int wv  = tid >> 6;
  const int l   = tid & 63;
  const int b   = blockIdx.y;
  const int m0  = blockIdx.x * TILE;
  const int g0  = m0 - 20;
  const bool has_o = (bm != 0.f);

  if (!first) {
    float p0 = 0.f, p1 = 0.f, p2 = 0.f, p3 = 0.f;
    for (int k = 0; k < 4; ++k) {
      const int ch0 = k << 4;
      const float* pcb = Xc + ((size_t)b * C_ + ch0) * M_;
      const float* pob = Xo + ((size_t)b * C_ + ch0) * M_;
      __syncthreads();
      for (int f = tid; f < NQ4; f += NT) {
        const int c  = f / Q4PC;
        const int i4 = f - c * Q4PC;
        const int g  = g0 + (i4 << 2);
        const float* pa = pcb + (size_t)c * M_ + g;
        const float* pb = pob + (size_t)c * M_ + g;
        float ax, ay, az, aw, ox, oy, oz, ow;
        if (g >= 0 && g + 3 < M_) {
          const float4 a = *(const float4*)pa;
          ax = a.x; ay = a.y; az = a.z; aw = a.w;
          if (has_o) {
            const float4 o = *(const float4*)pb;
            ox = o.x; oy = o.y; oz = o.z; ow = o.w;
          } else { ox = oy = oz = ow = 0.f; }
        } else {
          ax = ay = az = aw = ox = oy = oz = ow = 0.f;
          if ((unsigned)(g+0) < (unsigned)M_) { ax = pa[0]; if (has_o) ox = pb[0]; }
          if ((unsigned)(g+1) < (unsigned)M_) { ay = pa[1]; if (has_o) oy = pb[1]; }
          if ((unsigned)(g+2) < (unsigned)M_) { az = pa[2]; if (has_o) oz = pb[2]; }
          if ((unsigned)(g+3) < (unsigned)M_) { aw = pa[3]; if (has_o) ow = pb[3]; }
        }
        float4 w4;
        w4.x = fmaf(bm, ox, bp * ax);
        w4.y = fmaf(bm, oy, bp * ay);
        w4.z = fmaf(bm, oz, bp * az);
        w4.w = fmaf(bm, ow, bp * aw);
        *(float4*)&xs[c][i4 << 2] = w4;
      }
      __syncthreads();
      #pragma unroll
      for (int j = 0; j < 4; ++j) {
        const int cloc = (wv << 2) + j;
        const int cg = __builtin_amdgcn_readfirstlane(ch0 + cloc);
        const float* hc = Hg + cg * K_;
        float w[24];
        #pragma unroll
        for (int kk = 0; kk < 6; ++kk) {
          const float4 v = *(const float4*)&xs[cloc][(l << 2) + (kk << 2)];
          w[4*kk+0] = v.x; w[4*kk+1] = v.y;
          w[4*kk+2] = v.z; w[4*kk+3] = v.w;
        }
        #pragma unroll
        for (int u = 0; u < 21; ++u) {
          const float hv = hc[20 - u];
          p0 = fmaf(w[u],     hv, p0);
          p1 = fmaf(w[u + 1], hv, p1);
          p2 = fmaf(w[u + 2], hv, p2);
          p3 = fmaf(w[u + 3], hv, p3);
        }
      }
    }
    *(float4*)&rp[wv][l << 2] = make_float4(p0, p1, p2, p3);
  }
  __syncthreads();

  {
    const int n = m0 + tid;
    float r = 0.f;
    if (n < N_) {
      r = y[(size_t)b * N_ + n];
      if (!first) r -= rp[0][tid] + rp[1][tid] + rp[2][tid] + rp[3][tid];
    }
    rs[tid] = r;
  }
  __syncthreads();

  if (l < 59 && (l << 2) < M_ - m0) {
    float wr[24];
    #pragma unroll
    for (int kk = 0; kk < 6; ++kk) {
      const float4 v = *(const float4*)&rs[(l << 2) + (kk << 2)];
      wr[4*kk+0] = v.x; wr[4*kk+1] = v.y;
      wr[4*kk+2] = v.z; wr[4*kk+3] = v.w;
    }
    #pragma unroll 4
    for (int cl = 0; cl < 16; ++cl) {
      const int cg = __builtin_amdgcn_readfirstlane((wv << 4) + cl);
      const size_t row = ((size_t)b * C_ + cg) * M_ + m0 + (l << 2);
      float xt0, xt1, xt2, xt3;
      if (!first) {
        const float4 a = *(const float4*)(Xc + row);
        float ox = 0.f, oy = 0.f, oz = 0.f, ow = 0.f;
        if (has_o) {
          const float4 o = *(const float4*)(Xo + row);
          ox = o.x; oy = o.y; oz = o.z; ow = o.w;
        }
        xt0 = fmaf(bm, ox, bp * a.x);
        xt1 = fmaf(bm, oy, bp * a.y);
        xt2 = fmaf(bm, oz, bp * a.z);
        xt3 = fmaf(bm, ow, bp * a.w);
      } else { xt0 = xt1 = xt2 = xt3 = 0.f; }
      const float* hc = Hg + cg * K_;
      float a0 = 0.f, a1 = 0.f, a2 = 0.f, a3 = 0.f;
      #pragma unroll
      for (int u = 0; u < 21; ++u) {
        const float hv = hc[u];
        a0 = fmaf(wr[u],     hv, a0);
        a1 = fmaf(wr[u + 1], hv, a1);
        a2 = fmaf(wr[u + 2], hv, a2);
        a3 = fmaf(wr[u + 3], hv, a3);
      }
      const float o0 = fmaxf(fmaf(a0, 0.1f, xt0) - 0.01f, 0.f);
      const float o1 = fmaxf(fmaf(a1, 0.1f, xt1) - 0.01f, 0.f);
      const float o2 = fmaxf(fmaf(a2, 0.1f, xt2) - 0.01f, 0.f);
      const float o3 = fmaxf(fmaf(a3, 0.1f, xt3) - 0.01f, 0.f);
      *(float4*)(Xw + row) = make_float4(o0, o1, o2, o3);
    }
  }
}

#define TA 1024
#define CC 16

__global__ __launch_bounds__(NT) void convT_kernel(
    const float* __restrict__ X, const float* __restrict__ y,
    const float* __restrict__ Hg, float* __restrict__ out,
    const int use_y, const float sign)
{
  __shared__ float xs[CC][TA + 20];
  __shared__ float hs[C_][K_];
  const int tid = threadIdx.x;
  const int b = blockIdx.y;
  const int n0 = blockIdx.x * TA;

  for (int f = tid; f < C_ * K_; f += NT) hs[f / K_][f % K_] = sign * Hg[f];

  float acc[4];
  if (use_y) {
    const float4 v = *(const float4*)(y + (size_t)b * N_ + n0 + tid * 4);
    acc[0] = v.x; acc[1] = v.y; acc[2] = v.z; acc[3] = v.w;
  } else {
    acc[0] = acc[1] = acc[2] = acc[3] = 0.f;
  }
  const bool interior = (n0 >= 20) && (n0 + TA - 1 <= M_ - 1);
  const int QROW = (TA + 20) / 4;
  for (int cb = 0; cb < C_; cb += CC) {
    __syncthreads();
    for (int f = tid; f < CC * QROW; f += NT) {
      const int c = f / QROW;
      const int i = (f % QROW) * 4;
      const int gx = n0 - 20 + i;
      const float* src = X + ((size_t)(b * C_ + cb + c)) * M_ + gx;
      float4 v;
      if (interior) {
        v = *(const float4*)src;
      } else {
        v.x = (gx >= 0     && gx < M_)     ? src[0] : 0.f;
        v.y = (gx + 1 >= 0 && gx + 1 < M_) ? src[1] : 0.f;
        v.z = (gx + 2 >= 0 && gx + 2 < M_) ? src[2] : 0.f;
        v.w = (gx + 3 >= 0 && gx + 3 < M_) ? src[3] : 0.f;
      }
      *(float4*)&xs[c][i] = v;
    }
    __syncthreads();
    for (int c = 0; c < CC; ++c) {
      float w[24];
      #pragma unroll
      for (int k = 0; k < 6; ++k) {
        const float4 v = *(const float4*)&xs[c][tid * 4 + k * 4];
        w[k*4] = v.x; w[k*4+1] = v.y; w[k*4+2] = v.z; w[k*4+3] = v.w;
      }
      const float* hr = hs[cb + c];
      #pragma unroll
      for (int j = 0; j < K_; ++j) {
        const float h = hr[j];
        acc[0] = fmaf(h, w[20 - j], acc[0]);
        acc[1] = fmaf(h, w[21 - j], acc[1]);
        acc[2] = fmaf(h, w[22 - j], acc[2]);
        acc[3] = fmaf(h, w[23 - j], acc[3]);
      }
    }
  }
  *(float4*)(out + (size_t)b * N_ + n0 + tid * 4) =
      make_float4(acc[0], acc[1], acc[2], acc[3]);
}

extern "C" void kernel_launch(void* const* d_in, const int* in_sizes, int n_in,
                              void* d_out, int out_size, void* d_ws, size_t ws_size,
                              hipStream_t stream)
{
  const float* y = (const float*)d_in[0];   // [B,1,N] fp32
  const float* H = (const float*)d_in[1];   // [C,1,K] fp32
  float* out  = (float*)d_out;
  float* outy = out;                         // [B,N] y_hat region
  float* outx = out + (size_t)B_ * N_;       // [B,C,M] x region

  const size_t SZ = (size_t)B_ * C_ * M_;    // floats per x buffer
  const size_t UP = (size_t)B_ * NBLK * UPW; // floats per u buffer (573440)

  // FISTA momentum: betas[t] = (s_t - 1)/s_{t+1}, s_0 = 1 (betas[0] = 0)
  float betas[T_];
  double s = 1.0;
  for (int t = 0; t < T_; ++t) {
    const double sn = (1.0 + sqrt(1.0 + 4.0 * s * s)) * 0.5;
    betas[t] = (float)((s - 1.0) / sn);
    s = sn;
  }

  float* P[3] = { (float*)d_ws, (float*)d_ws + SZ, outx };
  const dim3 blk(NT);

  if (ws_size >= (2 * SZ + 3 * UP) * sizeof(float)) {
    // -------- round-8 path: u-recursion, no halo staging --------
    float* U[3] = { (float*)d_ws + 2 * SZ,
                    (float*)d_ws + 2 * SZ + UP,
                    (float*)d_ws + 2 * SZ + 2 * UP };
    const dim3 gF(NBLK, B_);   // 70 x 32
    for (int t = 0; t < T_; ++t) {
      const float beta = (t >= 1) ? betas[t - 1] : 0.f;
      const float* Xc = P[(t + 2) % 3];
      const float* Xo = (beta != 0.f) ? P[(t + 1) % 3] : P[(t + 2) % 3];
      float*       Xw = P[t % 3];
      const float* Ut = U[(t + 2) % 3];
      const float* Uo = (beta != 0.f) ? U[(t + 1) % 3] : U[(t + 2) % 3];
      float*       Uw = U[t % 3];
      fused_step2_kernel<<<gF, blk, 0, stream>>>(
          Xc, Xo, Xw, Ut, Uo, Uw, y, H, 1.f + beta, -beta, t == 0);
    }
    const dim3 gY(N_ / 256, B_);   // 64 x 32
    yhat_combine_kernel<<<gY, blk, 0, stream>>>(U[(T_ - 1) % 3], outy);
  } else {
    // -------- round-5 proven fallback --------
    const dim3 gF((M_ + TILE - 1) / TILE, B_);
    for (int t = 0; t < T_; ++t) {
      const float beta = (t >= 1) ? betas[t - 1] : 0.f;
      const float* Xc = P[(t + 2) % 3];
      const float* Xo = (beta != 0.f) ? P[(t + 1) % 3] : P[(t + 2) % 3];
      float*       Xw = P[t % 3];
      fused_step_r5_kernel<<<gF, blk, 0, stream>>>(Xc, Xo, Xw, y, H,
                                                   1.f + beta, -beta, t == 0);
    }
    const dim3 gA(N_ / TA, B_);
    convT_kernel<<<gA, blk, 0, stream>>>(outx, y, H, outy, 0, 1.f);
  }
}

// Round 9
// 2872.682 us; speedup vs baseline: 3.7837x; 1.0426x over previous
//
#include <hip/hip_runtime.h>
#include <math.h>

// Problem constants (from reference)
#define B_ 32
#define N_ 16384
#define K_ 21
#define C_ 64
#define M_ (N_ - K_ + 1)   // 16364
#define T_ 30
// L = 10.0, LAM = 0.1  ->  1/L = 0.1, LAM/L = 0.01

#define TILE 236    // x outputs per block
#define NBLK 70     // blocks per batch in m  (70*236 >= M_)
#define UPW  256    // u-partial slots per block (res width)
#define XRW  284    // LDS x row width: 20 pad + 236 + 24 pad, +4 bank stagger
#define NT   256    // 4 waves

// Compiler-level ordering fence for same-wave LDS RAW (cross-lane within a
// wave). HW executes a wave's DS ops in program order, so no s_waitcnt is
// needed; we only must stop the compiler from reordering the ds_read above
// the ds_write. Emits no instructions.
__device__ __forceinline__ void wave_lds_fence() {
  asm volatile("" ::: "memory");
  __builtin_amdgcn_wave_barrier();
}

// ---------------- fused step (u-recursion) ----------------
// u_t = convT(x_t) kept as per-block partials up[B][NBLK][UPW] (<=2 blocks
// overlap per position -> exact deterministic sum at read time, no atomics).
// Per block (b, x): res tile from y/u (tiny, L2-hot); conv(res)+shrink from
// rs in LDS; x_{t+1} written to global AND to LDS rows; convT partials of
// the new tile accumulate this block's up_{t+1} slots. NO global halo
// staging anywhere. In the chunk loop, each wave touches ONLY its own xr
// rows (4wv..4wv+3): those deps are within-wave -> wave_lds_fence(), not
// __syncthreads(). Only rs (after init) and rp (before final sum) are
// cross-wave -> 2 real barriers per kernel.
__global__ __launch_bounds__(NT) void fused_step2_kernel(
    const float* __restrict__ Xc, const float* __restrict__ Xo,
    float* __restrict__ Xw,
    const float* __restrict__ Ut, const float* __restrict__ Uo,
    float* __restrict__ Uw,
    const float* __restrict__ y, const float* __restrict__ Hg,
    const float bp, const float bm, const int first)
{
  __shared__ float rs[256];        // residual row
  __shared__ float xr[16][XRW];    // x_{t+1} chunk rows (18176 B)
  __shared__ float rp[4][256];     // per-wave convT partials

  const int tid = threadIdx.x;
  const int wv  = tid >> 6;
  const int l   = tid & 63;
  const int b   = blockIdx.y;
  const int x   = blockIdx.x;
  const int m0  = x * TILE;
  const bool has_o = (bm != 0.f);

  // ---- zero xr (pads + last-block tail stay zero forever) ----
  {
    float4* p = (float4*)&xr[0][0];
    #pragma unroll
    for (int s = 0; s < 5; ++s) {
      const int idx = tid + (s << 8);
      if (idx < 16 * XRW / 4) p[idx] = make_float4(0.f, 0.f, 0.f, 0.f);
    }
  }

  // ---- residual: res = y - bp*u_t - bm*u_{t-1} ----
  {
    const int n = m0 + tid;
    float r = 0.f;
    if (n < N_) {
      r = y[(size_t)b * N_ + n];
      if (!first) {
        const float* Ub = Ut + (size_t)b * NBLK * UPW;
        float ut;
        if (tid >= 236) {
          ut = Ub[(x + 1) * UPW + tid - 236] + Ub[x * UPW + tid];
        } else {
          ut = Ub[x * UPW + tid];
          if (tid < 20 && x > 0) ut += Ub[(x - 1) * UPW + 236 + tid];
        }
        r -= bp * ut;
        if (has_o) {
          const float* Vb = Uo + (size_t)b * NBLK * UPW;
          float uo;
          if (tid >= 236) {
            uo = Vb[(x + 1) * UPW + tid - 236] + Vb[x * UPW + tid];
          } else {
            uo = Vb[x * UPW + tid];
            if (tid < 20 && x > 0) uo += Vb[(x - 1) * UPW + 236 + tid];
          }
          r -= bm * uo;
        }
      }
    }
    rs[tid] = r;
  }
  __syncthreads();   // rs + xr zero-init are cross-wave

  const int rem = M_ - m0;
  const bool act = (l < 59) && ((l << 2) < rem);
  float p0 = 0.f, p1 = 0.f, p2 = 0.f, p3 = 0.f;

  for (int k = 0; k < 4; ++k) {   // 4 chunks x 16 channels
    // ---- phase A: conv(res) + shrink; write x to global + LDS row ----
    if (act) {
      float wr[24];
      #pragma unroll
      for (int kk = 0; kk < 6; ++kk) {
        const float4 v = *(const float4*)&rs[(l << 2) + (kk << 2)];
        wr[4*kk+0] = v.x; wr[4*kk+1] = v.y;
        wr[4*kk+2] = v.z; wr[4*kk+3] = v.w;
      }
      #pragma unroll
      for (int j = 0; j < 4; ++j) {
        const int row = (wv << 2) + j;
        const int cg  = __builtin_amdgcn_readfirstlane((k << 4) + row);
        const size_t gro = ((size_t)b * C_ + cg) * M_ + m0 + (l << 2);
        float xt0 = 0.f, xt1 = 0.f, xt2 = 0.f, xt3 = 0.f;
        if (!first) {
          const float4 a = *(const float4*)(Xc + gro);
          float ox = 0.f, oy = 0.f, oz = 0.f, ow = 0.f;
          if (has_o) {
            const float4 o = *(const float4*)(Xo + gro);
            ox = o.x; oy = o.y; oz = o.z; ow = o.w;
          }
          xt0 = fmaf(bm, ox, bp * a.x);
          xt1 = fmaf(bm, oy, bp * a.y);
          xt2 = fmaf(bm, oz, bp * a.z);
          xt3 = fmaf(bm, ow, bp * a.w);
        }
        const float* hc = Hg + cg * K_;   // uniform -> s_loads
        float g0 = 0.f, g1 = 0.f, g2 = 0.f, g3 = 0.f;
        #pragma unroll
        for (int u = 0; u < 21; ++u) {
          const float hv = hc[u];
          g0 = fmaf(wr[u],     hv, g0);
          g1 = fmaf(wr[u + 1], hv, g1);
          g2 = fmaf(wr[u + 2], hv, g2);
          g3 = fmaf(wr[u + 3], hv, g3);
        }
        const float o0 = fmaxf(fmaf(g0, 0.1f, xt0) - 0.01f, 0.f);
        const float o1 = fmaxf(fmaf(g1, 0.1f, xt1) - 0.01f, 0.f);
        const float o2 = fmaxf(fmaf(g2, 0.1f, xt2) - 0.01f, 0.f);
        const float o3 = fmaxf(fmaf(g3, 0.1f, xt3) - 0.01f, 0.f);
        *(float4*)(Xw + gro) = make_float4(o0, o1, o2, o3);
        *(float4*)&xr[row][20 + (l << 2)] = make_float4(o0, o1, o2, o3);
      }
    }
    wave_lds_fence();   // xr rows are wave-private: order write -> read

    // ---- phase B: convT partials of the new x tile (LDS windows) ----
    #pragma unroll
    for (int j = 0; j < 4; ++j) {
      const int row = (wv << 2) + j;
      const int cg  = __builtin_amdgcn_readfirstlane((k << 4) + row);
      const float* hc = Hg + cg * K_;
      float w[24];
      #pragma unroll
      for (int kk = 0; kk < 6; ++kk) {
        const float4 v = *(const float4*)&xr[row][(l << 2) + (kk << 2)];
        w[4*kk+0] = v.x; w[4*kk+1] = v.y;
        w[4*kk+2] = v.z; w[4*kk+3] = v.w;
      }
      #pragma unroll
      for (int u = 0; u < 21; ++u) {
        const float hv = hc[20 - u];
        p0 = fmaf(w[u],     hv, p0);
        p1 = fmaf(w[u + 1], hv, p1);
        p2 = fmaf(w[u + 2], hv, p2);
        p3 = fmaf(w[u + 3], hv, p3);
      }
    }
    wave_lds_fence();   // before next chunk's phase A overwrites rows
  }

  rp[wv][(l<<2)+0] = p0; rp[wv][(l<<2)+1] = p1;
  rp[wv][(l<<2)+2] = p2; rp[wv][(l<<2)+3] = p3;
  __syncthreads();   // rp is cross-wave

  // one deterministic write per slot
  Uw[((size_t)b * NBLK + x) * UPW + tid] =
      rp[0][tid] + rp[1][tid] + rp[2][tid] + rp[3][tid];
}

// y_hat[n] = u_30(n) from per-block partials (<=2 contributions)
__global__ __launch_bounds__(NT) void yhat_combine_kernel(
    const float* __restrict__ Uw, float* __restrict__ outy)
{
  const int tid = threadIdx.x;
  const int n = blockIdx.x * 256 + tid;
  const int b = blockIdx.y;
  const int x = n / 236;
  const int i = n - x * 236;
  const float* Ub = Uw + (size_t)b * NBLK * UPW;
  float v = Ub[x * UPW + i];
  if (i < 20 && x > 0) v += Ub[(x - 1) * UPW + 236 + i];
  outy[(size_t)b * N_ + n] = v;
}

// ================= round-5 proven fallback path =================
#define XWID 276
#define Q4PC 69
#define NQ4  (16 * Q4PC)

__global__ __launch_bounds__(NT, 4) void fused_step_r5_kernel(
    const float* __restrict__ Xc, const float* __restrict__ Xo,
    float* __restrict__ Xw, const float* __restrict__ y,
    const float* __restrict__ Hg, const float bp, const float bm,
    const int first)
{
  __shared__ float xs[16][XWID];
  __shared__ float rp[4][256];
  __shared__ float rs[256];

  const int tid = threadIdx.x;
  const int wv  = tid >> 6;
  const int l   = tid & 63;
  const int b   = blockIdx.y;
  const int m0  = blockIdx.x * TILE;
  const int g0  = m0 - 20;
  const bool has_o = (bm != 0.f);

  if (!first) {
    float p0 = 0.f, p1 = 0.f, p2 = 0.f, p3 = 0.f;
    for (int k = 0; k < 4; ++k) {
      const int ch0 = k << 4;
      const float* pcb = Xc + ((size_t)b * C_ + ch0) * M_;
      const float* pob = Xo + ((size_t)b * C_ + ch0) * M_;
      __syncthreads();
      for (int f = tid; f < NQ4; f += NT) {
        const int c  = f / Q4PC;
        const int i4 = f - c * Q4PC;
        const int g  = g0 + (i4 << 2);
        const float* pa = pcb + (size_t)c * M_ + g;
        const float* pb = pob + (size_t)c * M_ + g;
        float ax, ay, az, aw, ox, oy, oz, ow;
        if (g >= 0 && g + 3 < M_) {
          const float4 a = *(const float4*)pa;
          ax = a.x; ay = a.y; az = a.z; aw = a.w;
          if (has_o) {
            const float4 o = *(const float4*)pb;
            ox = o.x; oy = o.y; oz = o.z; ow = o.w;
          } else { ox = oy = oz = ow = 0.f; }
        } else {
          ax = ay = az = aw = ox = oy = oz = ow = 0.f;
          if ((unsigned)(g+0) < (unsigned)M_) { ax = pa[0]; if (has_o) ox = pb[0]; }
          if ((unsigned)(g+1) < (unsigned)M_) { ay = pa[1]; if (has_o) oy = pb[1]; }
          if ((unsigned)(g+2) < (unsigned)M_) { az = pa[2]; if (has_o) oz = pb[2]; }
          if ((unsigned)(g+3) < (unsigned)M_) { aw = pa[3]; if (has_o) ow = pb[3]; }
        }
        float4 w4;
        w4.x = fmaf(bm, ox, bp * ax);
        w4.y = fmaf(bm, oy, bp * ay);
        w4.z = fmaf(bm, oz, bp * az);
        w4.w = fmaf(bm, ow, bp * aw);
        *(float4*)&xs[c][i4 << 2] = w4;
      }
      __syncthreads();
      #pragma unroll
      for (int j = 0; j < 4; ++j) {
        const int cloc = (wv << 2) + j;
        const int cg = __builtin_amdgcn_readfirstlane(ch0 + cloc);
        const float* hc = Hg + cg * K_;
        float w[24];
        #pragma unroll
        for (int kk = 0; kk < 6; ++kk) {
          const float4 v = *(const float4*)&xs[cloc][(l << 2) + (kk << 2)];
          w[4*kk+0] = v.x; w[4*kk+1] = v.y;
          w[4*kk+2] = v.z; w[4*kk+3] = v.w;
        }
        #pragma unroll
        for (int u = 0; u < 21; ++u) {
          const float hv = hc[20 - u];
          p0 = fmaf(w[u],     hv, p0);
          p1 = fmaf(w[u + 1], hv, p1);
          p2 = fmaf(w[u + 2], hv, p2);
          p3 = fmaf(w[u + 3], hv, p3);
        }
      }
    }
    *(float4*)&rp[wv][l << 2] = make_float4(p0, p1, p2, p3);
  }
  __syncthreads();

  {
    const int n = m0 + tid;
    float r = 0.f;
    if (n < N_) {
      r = y[(size_t)b * N_ + n];
      if (!first) r -= rp[0][tid] + rp[1][tid] + rp[2][tid] + rp[3][tid];
    }
    rs[tid] = r;
  }
  __syncthreads();

  if (l < 59 && (l << 2) < M_ - m0) {
    float wr[24];
    #pragma unroll
    for (int kk = 0; kk < 6; ++kk) {
      const float4 v = *(const float4*)&rs[(l << 2) + (kk << 2)];
      wr[4*kk+0] = v.x; wr[4*kk+1] = v.y;
      wr[4*kk+2] = v.z; wr[4*kk+3] = v.w;
    }
    #pragma unroll 4
    for (int cl = 0; cl < 16; ++cl) {
      const int cg = __builtin_amdgcn_readfirstlane((wv << 4) + cl);
      const size_t row = ((size_t)b * C_ + cg) * M_ + m0 + (l << 2);
      float xt0, xt1, xt2, xt3;
      if (!first) {
        const float4 a = *(const float4*)(Xc + row);
        float ox = 0.f, oy = 0.f, oz = 0.f, ow = 0.f;
        if (has_o) {
          const float4 o = *(const float4*)(Xo + row);
          ox = o.x; oy = o.y; oz = o.z; ow = o.w;
        }
        xt0 = fmaf(bm, ox, bp * a.x);
        xt1 = fmaf(bm, oy, bp * a.y);
        xt2 = fmaf(bm, oz, bp * a.z);
        xt3 = fmaf(bm, ow, bp * a.w);
      } else { xt0 = xt1 = xt2 = xt3 = 0.f; }
      const float* hc = Hg + cg * K_;
      float a0 = 0.f, a1 = 0.f, a2 = 0.f, a3 = 0.f;
      #pragma unroll
      for (int u = 0; u < 21; ++u) {
        const float hv = hc[u];
        a0 = fmaf(wr[u],     hv, a0);
        a1 = fmaf(wr[u + 1], hv, a1);
        a2 = fmaf(wr[u + 2], hv, a2);
        a3 = fmaf(wr[u + 3], hv, a3);
      }
      const float o0 = fmaxf(fmaf(a0, 0.1f, xt0) - 0.01f, 0.f);
      const float o1 = fmaxf(fmaf(a1, 0.1f, xt1) - 0.01f, 0.f);
      const float o2 = fmaxf(fmaf(a2, 0.1f, xt2) - 0.01f, 0.f);
      const float o3 = fmaxf(fmaf(a3, 0.1f, xt3) - 0.01f, 0.f);
      *(float4*)(Xw + row) = make_float4(o0, o1, o2, o3);
    }
  }
}

#define TA 1024
#define CC 16

__global__ __launch_bounds__(NT) void convT_kernel(
    const float* __restrict__ X, const float* __restrict__ y,
    const float* __restrict__ Hg, float* __restrict__ out,
    const int use_y, const float sign)
{
  __shared__ float xs[CC][TA + 20];
  __shared__ float hs[C_][K_];
  const int tid = threadIdx.x;
  const int b = blockIdx.y;
  const int n0 = blockIdx.x * TA;

  for (int f = tid; f < C_ * K_; f += NT) hs[f / K_][f % K_] = sign * Hg[f];

  float acc[4];
  if (use_y) {
    const float4 v = *(const float4*)(y + (size_t)b * N_ + n0 + tid * 4);
    acc[0] = v.x; acc[1] = v.y; acc[2] = v.z; acc[3] = v.w;
  } else {
    acc[0] = acc[1] = acc[2] = acc[3] = 0.f;
  }
  const bool interior = (n0 >= 20) && (n0 + TA - 1 <= M_ - 1);
  const int QROW = (TA + 20) / 4;
  for (int cb = 0; cb < C_; cb += CC) {
    __syncthreads();
    for (int f = tid; f < CC * QROW; f += NT) {
      const int c = f / QROW;
      const int i = (f % QROW) * 4;
      const int gx = n0 - 20 + i;
      const float* src = X + ((size_t)(b * C_ + cb + c)) * M_ + gx;
      float4 v;
      if (interior) {
        v = *(const float4*)src;
      } else {
        v.x = (gx >= 0     && gx < M_)     ? src[0] : 0.f;
        v.y = (gx + 1 >= 0 && gx + 1 < M_) ? src[1] : 0.f;
        v.z = (gx + 2 >= 0 && gx + 2 < M_) ? src[2] : 0.f;
        v.w = (gx + 3 >= 0 && gx + 3 < M_) ? src[3] : 0.f;
      }
      *(float4*)&xs[c][i] = v;
    }
    __syncthreads();
    for (int c = 0; c < CC; ++c) {
      float w[24];
      #pragma unroll
      for (int k = 0; k < 6; ++k) {
        const float4 v = *(const float4*)&xs[c][tid * 4 + k * 4];
        w[k*4] = v.x; w[k*4+1] = v.y; w[k*4+2] = v.z; w[k*4+3] = v.w;
      }
      const float* hr = hs[cb + c];
      #pragma unroll
      for (int j = 0; j < K_; ++j) {
        const float h = hr[j];
        acc[0] = fmaf(h, w[20 - j], acc[0]);
        acc[1] = fmaf(h, w[21 - j], acc[1]);
        acc[2] = fmaf(h, w[22 - j], acc[2]);
        acc[3] = fmaf(h, w[23 - j], acc[3]);
      }
    }
  }
  *(float4*)(out + (size_t)b * N_ + n0 + tid * 4) =
      make_float4(acc[0], acc[1], acc[2], acc[3]);
}

extern "C" void kernel_launch(void* const* d_in, const int* in_sizes, int n_in,
                              void* d_out, int out_size, void* d_ws, size_t ws_size,
                              hipStream_t stream)
{
  const float* y = (const float*)d_in[0];   // [B,1,N] fp32
  const float* H = (const float*)d_in[1];   // [C,1,K] fp32
  float* out  = (float*)d_out;
  float* outy = out;                         // [B,N] y_hat region
  float* outx = out + (size_t)B_ * N_;       // [B,C,M] x region

  const size_t SZ = (size_t)B_ * C_ * M_;    // floats per x buffer
  const size_t UP = (size_t)B_ * NBLK * UPW; // floats per u buffer (573440)

  // FISTA momentum: betas[t] = (s_t - 1)/s_{t+1}, s_0 = 1 (betas[0] = 0)
  float betas[T_];
  double s = 1.0;
  for (int t = 0; t < T_; ++t) {
    const double sn = (1.0 + sqrt(1.0 + 4.0 * s * s)) * 0.5;
    betas[t] = (float)((s - 1.0) / sn);
    s = sn;
  }

  float* P[3] = { (float*)d_ws, (float*)d_ws + SZ, outx };
  const dim3 blk(NT);

  if (ws_size >= (2 * SZ + 3 * UP) * sizeof(float)) {
    // -------- u-recursion path: no halo staging --------
    float* U[3] = { (float*)d_ws + 2 * SZ,
                    (float*)d_ws + 2 * SZ + UP,
                    (float*)d_ws + 2 * SZ + 2 * UP };
    const dim3 gF(NBLK, B_);   // 70 x 32
    for (int t = 0; t < T_; ++t) {
      const float beta = (t >= 1) ? betas[t - 1] : 0.f;
      const float* Xc = P[(t + 2) % 3];
      const float* Xo = (beta != 0.f) ? P[(t + 1) % 3] : P[(t + 2) % 3];
      float*       Xw = P[t % 3];
      const float* Ut = U[(t + 2) % 3];
      const float* Uo = (beta != 0.f) ? U[(t + 1) % 3] : U[(t + 2) % 3];
      float*       Uw = U[t % 3];
      fused_step2_kernel<<<gF, blk, 0, stream>>>(
          Xc, Xo, Xw, Ut, Uo, Uw, y, H, 1.f + beta, -beta, t == 0);
    }
    const dim3 gY(N_ / 256, B_);   // 64 x 32
    yhat_combine_kernel<<<gY, blk, 0, stream>>>(U[(T_ - 1) % 3], outy);
  } else {
    // -------- round-5 proven fallback --------
    const dim3 gF((M_ + TILE - 1) / TILE, B_);
    for (int t = 0; t < T_; ++t) {
      const float beta = (t >= 1) ? betas[t - 1] : 0.f;
      const float* Xc = P[(t + 2) % 3];
      const float* Xo = (beta != 0.f) ? P[(t + 1) % 3] : P[(t + 2) % 3];
      float*       Xw = P[t % 3];
      fused_step_r5_kernel<<<gF, blk, 0, stream>>>(Xc, Xo, Xw, y, H,
                                                   1.f + beta, -beta, t == 0);
    }
    const dim3 gA(N_ / TA, B_);
    convT_kernel<<<gA, blk, 0, stream>>>(outx, y, H, outy, 0, 1.f);
  }
}